// Round 9
// baseline (375.195 us; speedup 1.0000x reference)
//
#include <hip/hip_runtime.h>
#include <stdint.h>

#define T_TOK 2048
#define DIM   2048
#define FDIM  1024
#define NE    8
#define MAXT128 40

typedef __attribute__((ext_vector_type(8))) short short8;
typedef __attribute__((ext_vector_type(4))) float f32x4;

__device__ __forceinline__ unsigned short f2b(float f) {
  union { float f; unsigned int i; } x; x.f = f;
  unsigned int r = x.i + 0x7fffu + ((x.i >> 16) & 1u);
  return (unsigned short)(r >> 16);
}

__device__ __forceinline__ void async16(void* lds, const void* g) {
  __builtin_amdgcn_global_load_lds(
      (const __attribute__((address_space(1))) void*)g,
      (__attribute__((address_space(3))) void*)lds, 16, 0, 0);
}

// ---------------- router body (one wave per token) ----------------
__device__ __forceinline__ void router_body(
    int t, const float* __restrict__ x, const float* __restrict__ gw,
    float* __restrict__ topkw, int* __restrict__ topke, int* __restrict__ counts,
    float* __restrict__ logits_out, unsigned short* __restrict__ xb)
{
  int lane = threadIdx.x & 63;
  const float* xr = x + (size_t)t * DIM;
  unsigned short* xbr = xb + (size_t)t * DIM;
  float acc[NE];
#pragma unroll
  for (int e = 0; e < NE; e++) acc[e] = 0.f;
  for (int d = lane * 4; d < DIM; d += 256) {
    float4 xv = *(const float4*)(xr + d);
    ushort4 xo;
    xo.x = f2b(xv.x); xo.y = f2b(xv.y); xo.z = f2b(xv.z); xo.w = f2b(xv.w);
    *(ushort4*)(xbr + d) = xo;
#pragma unroll
    for (int e = 0; e < NE; e++) {
      float4 gv = *(const float4*)(gw + e * DIM + d);
      acc[e] += xv.x * gv.x + xv.y * gv.y + xv.z * gv.z + xv.w * gv.w;
    }
  }
#pragma unroll
  for (int off = 32; off > 0; off >>= 1) {
#pragma unroll
    for (int e = 0; e < NE; e++) acc[e] += __shfl_down(acc[e], off);
  }
  if (lane == 0) {
    float m = acc[0];
#pragma unroll
    for (int e = 1; e < NE; e++) m = fmaxf(m, acc[e]);
    float p[NE];
#pragma unroll
    for (int e = 0; e < NE; e++) p[e] = __expf(acc[e] - m);
    int e0 = 0;
#pragma unroll
    for (int e = 1; e < NE; e++) if (acc[e] > acc[e0]) e0 = e;
    int e1 = -1;
#pragma unroll
    for (int e = 0; e < NE; e++) if (e != e0 && (e1 < 0 || acc[e] > acc[e1])) e1 = e;
    float s = p[e0] + p[e1];
    topkw[t * 2] = p[e0] / s;
    topkw[t * 2 + 1] = p[e1] / s;
    topke[t * 2] = e0; topke[t * 2 + 1] = e1;
    atomicAdd(&counts[e0], 1);
    atomicAdd(&counts[e1], 1);
#pragma unroll
    for (int e = 0; e < NE; e++) logits_out[t * NE + e] = acc[e];
  }
}

__device__ __forceinline__ void cvt_body(const float* __restrict__ src,
                                         unsigned short* __restrict__ dst, int bid)
{
  size_t i = ((size_t)bid * 256 + threadIdx.x) * 8;
  float4 a = *(const float4*)(src + i);
  float4 b = *(const float4*)(src + i + 4);
  ushort4 o0, o1;
  o0.x = f2b(a.x); o0.y = f2b(a.y); o0.z = f2b(a.z); o0.w = f2b(a.w);
  o1.x = f2b(b.x); o1.y = f2b(b.y); o1.z = f2b(b.z); o1.w = f2b(b.w);
  *(ushort4*)(dst + i) = o0;
  *(ushort4*)(dst + i + 4) = o1;
}

// deep-ILP convert: 4 strided chunks per thread, 8 float4 loads in flight
__device__ __forceinline__ void cvt_body4(const float* __restrict__ src,
                                          unsigned short* __restrict__ dst, int lb)
{
  const size_t STRIDE = (size_t)2048 * 2048;   // floats per sweep (2048 blocks x 2048 floats)
  size_t base = ((size_t)lb * 256 + threadIdx.x) * 8;
  float4 a[4], b[4];
#pragma unroll
  for (int u = 0; u < 4; u++) {
    a[u] = *(const float4*)(src + base + (size_t)u * STRIDE);
    b[u] = *(const float4*)(src + base + (size_t)u * STRIDE + 4);
  }
#pragma unroll
  for (int u = 0; u < 4; u++) {
    ushort4 o0, o1;
    o0.x = f2b(a[u].x); o0.y = f2b(a[u].y); o0.z = f2b(a[u].z); o0.w = f2b(a[u].w);
    o1.x = f2b(b[u].x); o1.y = f2b(b[u].y); o1.z = f2b(b[u].z); o1.w = f2b(b[u].w);
    *(ushort4*)(dst + base + (size_t)u * STRIDE) = o0;
    *(ushort4*)(dst + base + (size_t)u * STRIDE + 4) = o1;
  }
}

// ---------------- fused front: router (512 blocks) + 3 deep-ILP converts ----------------
__global__ __launch_bounds__(256) void front_k(
    const float* __restrict__ x, const float* __restrict__ gw,
    float* __restrict__ topkw, int* __restrict__ topke, int* __restrict__ counts,
    float* __restrict__ logits_out, unsigned short* __restrict__ xb,
    const float* __restrict__ wg, unsigned short* __restrict__ wgb,
    const float* __restrict__ wu, unsigned short* __restrict__ wub,
    const float* __restrict__ wd, unsigned short* __restrict__ wdb)
{
  int bid = blockIdx.x;
  if (bid < 512) {
    int wave = threadIdx.x >> 6;
    router_body(bid * 4 + wave, x, gw, topkw, topke, counts, logits_out, xb);
  } else {
    bid -= 512;
    int tb = bid >> 11;          // tensor id (2048 blocks each)
    int lb = bid & 2047;
    if (tb == 0)      cvt_body4(wg, wgb, lb);
    else if (tb == 1) cvt_body4(wu, wub, lb);
    else              cvt_body4(wd, wdb, lb);
  }
}

// standalone router (fallback paths)
__global__ __launch_bounds__(256) void router_k(
    const float* __restrict__ x, const float* __restrict__ gw,
    float* __restrict__ topkw, int* __restrict__ topke, int* __restrict__ counts,
    float* __restrict__ logits_out, unsigned short* __restrict__ xb)
{
  int wave = threadIdx.x >> 6;
  router_body(blockIdx.x * 4 + wave, x, gw, topkw, topke, counts, logits_out, xb);
}

// plain converts (fallback paths)
__global__ __launch_bounds__(256) void cvt2_k(const float* __restrict__ sA,
                                              unsigned short* __restrict__ dA,
                                              const float* __restrict__ sB,
                                              unsigned short* __restrict__ dB)
{
  int bid = blockIdx.x;
  if (bid < 8192) cvt_body(sA, dA, bid);
  else            cvt_body(sB, dB, bid - 8192);
}

__global__ __launch_bounds__(256) void cvt_w_k(const float* __restrict__ src,
                                               unsigned short* __restrict__ dst)
{
  cvt_body(src, dst, blockIdx.x);
}

// ---------------- fused scan + scatter (1 block) ----------------
__global__ __launch_bounds__(256) void scan_scatter_k(
    const int* __restrict__ counts, const int* __restrict__ topke,
    int4* __restrict__ tiles128, int* __restrict__ ntiles128,
    int* __restrict__ perm, int* __restrict__ slot_of)
{
  __shared__ int cur[NE];
  int tid = threadIdx.x;
  if (tid == 0) {
    int o = 0, nt2 = 0;
    for (int e = 0; e < NE; e++) {
      cur[e] = o;
      int c = counts[e];
      for (int r = 0; r < c; r += 128) {
        int rows = c - r < 128 ? c - r : 128;
        tiles128[nt2++] = make_int4(e, o + r, rows, 0);
      }
      o += c;
    }
    *ntiles128 = nt2;
  }
  __syncthreads();
  for (int i = tid; i < T_TOK * 2; i += 256) {
    int e = topke[i];
    int s = atomicAdd(&cur[e], 1);
    perm[s] = i;
    slot_of[i] = s;
  }
}

// ========== bf16 path: BM=128, BK=32, 2-phase dbuf, XCD-pinned grids ==========
// blockIdx.x = column panel (f0/d0), blockIdx.y = row tile. XCD = linear_id % 8
// = panel % 8 -> all blocks sharing a weight panel land on one XCD's L2.

// GEMM1: H[slot,f] = rw * silu(x@Wg^T) * (x@Wu^T)   BM=128, BN=64 per tensor
__global__ __launch_bounds__(256) void gemm1_bf_k(
    const unsigned short* __restrict__ xb,
    const unsigned short* __restrict__ wgb,
    const unsigned short* __restrict__ wub,
    const int* __restrict__ perm, const float* __restrict__ topkw,
    const int4* __restrict__ tiles, const int* __restrict__ ntiles,
    unsigned short* __restrict__ H)
{
  __shared__ short As[2][128 * 32];
  __shared__ short Bgs[2][64 * 32];
  __shared__ short Bus[2][64 * 32];
  __shared__ int rowtok[128];
  __shared__ float roww[128];

  if (blockIdx.y >= *ntiles) return;
  int4 tm = tiles[blockIdx.y];
  int e = tm.x, row0 = tm.y, nrows = tm.z;
  int tid = threadIdx.x;
  if (tid < 128) {
    int r = tid < nrows ? tid : (nrows - 1);
    int pid = perm[row0 + r];
    rowtok[tid] = pid >> 1;
    roww[tid] = topkw[pid];
  }
  __syncthreads();

  int f0 = blockIdx.x * 64;
  int crow = tid >> 2;            // 0..63
  int ccol = (tid & 3) * 8;
  const unsigned short* a0 = xb + (size_t)rowtok[crow] * DIM + ccol;
  const unsigned short* a1 = xb + (size_t)rowtok[crow + 64] * DIM + ccol;
  const unsigned short* bg = wgb + ((size_t)e * FDIM + f0 + crow) * DIM + ccol;
  const unsigned short* bu = wub + ((size_t)e * FDIM + f0 + crow) * DIM + ccol;

  int wave = tid >> 6, lane = tid & 63;
  int wm = wave >> 1, wn = wave & 1;
  int lrow = lane & 15, quad = lane >> 4;

  f32x4 accg[4][2], accu[4][2];
#pragma unroll
  for (int i = 0; i < 4; i++)
#pragma unroll
    for (int j = 0; j < 2; j++) {
      accg[i][j] = (f32x4){0.f, 0.f, 0.f, 0.f};
      accu[i][j] = (f32x4){0.f, 0.f, 0.f, 0.f};
    }

  const int aoff = (wm * 64 + lrow) * 32 + quad * 8;
  const int boff = (wn * 32 + lrow) * 32 + quad * 8;

#define STAGE1(b, k)                                 \
  do {                                               \
    async16(&As[b][tid * 8], a0 + (k));              \
    async16(&As[b][(256 + tid) * 8], a1 + (k));      \
    async16(&Bgs[b][tid * 8], bg + (k));             \
    async16(&Bus[b][tid * 8], bu + (k));             \
  } while (0)

  STAGE1(0, 0);

#pragma unroll 1
  for (int k0 = 0; k0 < DIM; k0 += 32) {
    int b = (k0 >> 5) & 1;
    __syncthreads();                       // buf b ready (vmcnt drained at barrier)
    if (k0 + 32 < DIM) STAGE1(b ^ 1, k0 + 32);   // prefetch overlaps MFMA below
    const short* arp = &As[0][0]  + b * (128 * 32) + aoff;
    const short* bgp = &Bgs[0][0] + b * (64 * 32) + boff;
    const short* bup = &Bus[0][0] + b * (64 * 32) + boff;
    short8 af[4], bgf[2], buf2[2];
#pragma unroll
    for (int i = 0; i < 4; i++) af[i] = *(const short8*)(arp + i * 16 * 32);
#pragma unroll
    for (int j = 0; j < 2; j++) {
      bgf[j]  = *(const short8*)(bgp + j * 16 * 32);
      buf2[j] = *(const short8*)(bup + j * 16 * 32);
    }
#pragma unroll
    for (int i = 0; i < 4; i++)
#pragma unroll
      for (int j = 0; j < 2; j++) {
        accg[i][j] = __builtin_amdgcn_mfma_f32_16x16x32_bf16(af[i], bgf[j], accg[i][j], 0, 0, 0);
        accu[i][j] = __builtin_amdgcn_mfma_f32_16x16x32_bf16(af[i], buf2[j], accu[i][j], 0, 0, 0);
      }
  }
#undef STAGE1

#pragma unroll
  for (int i = 0; i < 4; i++) {
#pragma unroll
    for (int reg = 0; reg < 4; reg++) {
      int r = wm * 64 + i * 16 + quad * 4 + reg;
      if (r < nrows) {
        float w = roww[r];
#pragma unroll
        for (int j = 0; j < 2; j++) {
          float g = accg[i][j][reg], u = accu[i][j][reg];
          float h = g * u * w / (1.f + __expf(-g));
          H[(size_t)(row0 + r) * FDIM + f0 + wn * 32 + j * 16 + lrow] = f2b(h);
        }
      }
    }
  }
}

// GEMM2: O[slot,d] = H[slot,:] @ Wd[e]^T   BM=128, BN=128, no atomics
__global__ __launch_bounds__(256) void gemm2_bf_k(
    const unsigned short* __restrict__ H,
    const unsigned short* __restrict__ wdb,
    const int4* __restrict__ tiles, const int* __restrict__ ntiles,
    float* __restrict__ O)
{
  __shared__ short Hs[2][128 * 32];
  __shared__ short Bs[2][128 * 32];

  if (blockIdx.y >= *ntiles) return;
  int4 tm = tiles[blockIdx.y];
  int e = tm.x, row0 = tm.y, nrows = tm.z;
  int tid = threadIdx.x;

  int d0 = blockIdx.x * 128;
  int crow = tid >> 2, ccol = (tid & 3) * 8;
  const unsigned short* a0 = H + (size_t)(row0 + crow) * FDIM + ccol;
  const unsigned short* a1 = H + (size_t)(row0 + crow + 64) * FDIM + ccol;
  const unsigned short* b0 = wdb + ((size_t)e * DIM + d0 + crow) * FDIM + ccol;
  const unsigned short* b1 = b0 + (size_t)64 * FDIM;

  int wave = tid >> 6, lane = tid & 63;
  int wm = wave >> 1, wn = wave & 1;
  int lrow = lane & 15, quad = lane >> 4;

  f32x4 acc[4][4];
#pragma unroll
  for (int i = 0; i < 4; i++)
#pragma unroll
    for (int j = 0; j < 4; j++) acc[i][j] = (f32x4){0.f, 0.f, 0.f, 0.f};

  const int aoff = (wm * 64 + lrow) * 32 + quad * 8;
  const int boff = (wn * 64 + lrow) * 32 + quad * 8;

#define STAGE2(b, k)                                 \
  do {                                               \
    async16(&Hs[b][tid * 8], a0 + (k));              \
    async16(&Hs[b][(256 + tid) * 8], a1 + (k));      \
    async16(&Bs[b][tid * 8], b0 + (k));              \
    async16(&Bs[b][(256 + tid) * 8], b1 + (k));      \
  } while (0)

  STAGE2(0, 0);

#pragma unroll 1
  for (int k0 = 0; k0 < FDIM; k0 += 32) {
    int b = (k0 >> 5) & 1;
    __syncthreads();
    if (k0 + 32 < FDIM) STAGE2(b ^ 1, k0 + 32);
    const short* arp = &Hs[0][0] + b * (128 * 32) + aoff;
    const short* brp = &Bs[0][0] + b * (128 * 32) + boff;
    short8 af[4], bf[4];
#pragma unroll
    for (int i = 0; i < 4; i++) af[i] = *(const short8*)(arp + i * 16 * 32);
#pragma unroll
    for (int j = 0; j < 4; j++) bf[j] = *(const short8*)(brp + j * 16 * 32);
#pragma unroll
    for (int i = 0; i < 4; i++)
#pragma unroll
      for (int j = 0; j < 4; j++)
        acc[i][j] = __builtin_amdgcn_mfma_f32_16x16x32_bf16(af[i], bf[j], acc[i][j], 0, 0, 0);
  }
#undef STAGE2

#pragma unroll
  for (int i = 0; i < 4; i++) {
#pragma unroll
    for (int reg = 0; reg < 4; reg++) {
      int r = wm * 64 + i * 16 + quad * 4 + reg;
      if (r < nrows) {
#pragma unroll
        for (int j = 0; j < 4; j++) {
          O[(size_t)(row0 + r) * DIM + d0 + wn * 64 + j * 16 + lrow] = acc[i][j][reg];
        }
      }
    }
  }
}

// combine: out[t,:] = O[slot0(t),:] + O[slot1(t),:]
__global__ __launch_bounds__(256) void combine_k(
    const float* __restrict__ O, const int* __restrict__ slot_of,
    float* __restrict__ out)
{
  int t = blockIdx.x;
  int d = threadIdx.x * 8;
  int s0 = slot_of[2 * t], s1 = slot_of[2 * t + 1];
  const float4* p0 = (const float4*)(O + (size_t)s0 * DIM + d);
  const float4* p1 = (const float4*)(O + (size_t)s1 * DIM + d);
  float4 a0 = p0[0], a1 = p0[1], c0 = p1[0], c1 = p1[1];
  float4 r0, r1;
  r0.x = a0.x + c0.x; r0.y = a0.y + c0.y; r0.z = a0.z + c0.z; r0.w = a0.w + c0.w;
  r1.x = a1.x + c1.x; r1.y = a1.y + c1.y; r1.z = a1.z + c1.z; r1.w = a1.w + c1.w;
  float4* po = (float4*)(out + (size_t)t * DIM + d);
  po[0] = r0; po[1] = r1;
}

// ================= fp32-weight fallback path (proven) =================

__global__ __launch_bounds__(256) void gemm1_f32_k(
    const unsigned short* __restrict__ xb,
    const float* __restrict__ wg,
    const float* __restrict__ wu,
    const int* __restrict__ perm, const float* __restrict__ topkw,
    const int4* __restrict__ tiles, const int* __restrict__ ntiles,
    unsigned short* __restrict__ H)
{
  __shared__ short As[128 * 32];
  __shared__ short Bgs[64 * 32];
  __shared__ short Bus[64 * 32];
  __shared__ int rowtok[128];
  __shared__ float roww[128];

  if (blockIdx.x >= *ntiles) return;
  int4 tm = tiles[blockIdx.x];
  int e = tm.x, row0 = tm.y, nrows = tm.z;
  int tid = threadIdx.x;
  if (tid < 128) {
    int r = tid < nrows ? tid : (nrows - 1);
    int pid = perm[row0 + r];
    rowtok[tid] = pid >> 1;
    roww[tid] = topkw[pid];
  }
  __syncthreads();

  int f0 = blockIdx.y * 64;
  int crow = tid >> 2;
  int ccol = (tid & 3) * 8;
  const unsigned short* a0 = xb + (size_t)rowtok[crow] * DIM + ccol;
  const unsigned short* a1 = xb + (size_t)rowtok[crow + 64] * DIM + ccol;
  const float* bg32 = wg + ((size_t)e * FDIM + f0 + crow) * DIM + ccol;
  const float* bu32 = wu + ((size_t)e * FDIM + f0 + crow) * DIM + ccol;
  short* as0 = As + tid * 8;
  short* as1 = As + (256 + tid) * 8;

  int wave = tid >> 6, lane = tid & 63;
  int wm = wave >> 1, wn = wave & 1;
  int lrow = lane & 15, quad = lane >> 4;

  f32x4 accg[4][2], accu[4][2];
#pragma unroll
  for (int i = 0; i < 4; i++)
#pragma unroll
    for (int j = 0; j < 2; j++) {
      accg[i][j] = (f32x4){0.f, 0.f, 0.f, 0.f};
      accu[i][j] = (f32x4){0.f, 0.f, 0.f, 0.f};
    }

  const short* arp = As + (wm * 64 + lrow) * 32 + quad * 8;
  const short* bgp = Bgs + (wn * 32 + lrow) * 32 + quad * 8;
  const short* bup = Bus + (wn * 32 + lrow) * 32 + quad * 8;

#pragma unroll 1
  for (int k0 = 0; k0 < DIM; k0 += 32) {
    async16(as0, a0 + k0);
    async16(as1, a1 + k0);
    float4 g0 = *(const float4*)(bg32 + k0);
    float4 g1 = *(const float4*)(bg32 + k0 + 4);
    float4 u0 = *(const float4*)(bu32 + k0);
    float4 u1 = *(const float4*)(bu32 + k0 + 4);
    short8 gs, us;
    gs[0] = f2b(g0.x); gs[1] = f2b(g0.y); gs[2] = f2b(g0.z); gs[3] = f2b(g0.w);
    gs[4] = f2b(g1.x); gs[5] = f2b(g1.y); gs[6] = f2b(g1.z); gs[7] = f2b(g1.w);
    us[0] = f2b(u0.x); us[1] = f2b(u0.y); us[2] = f2b(u0.z); us[3] = f2b(u0.w);
    us[4] = f2b(u1.x); us[5] = f2b(u1.y); us[6] = f2b(u1.z); us[7] = f2b(u1.w);
    *(short8*)(Bgs + tid * 8) = gs;
    *(short8*)(Bus + tid * 8) = us;
    __syncthreads();
    short8 af[4], bgf[2], buf2[2];
#pragma unroll
    for (int i = 0; i < 4; i++) af[i] = *(const short8*)(arp + i * 16 * 32);
#pragma unroll
    for (int j = 0; j < 2; j++) {
      bgf[j]  = *(const short8*)(bgp + j * 16 * 32);
      buf2[j] = *(const short8*)(bup + j * 16 * 32);
    }
#pragma unroll
    for (int i = 0; i < 4; i++)
#pragma unroll
      for (int j = 0; j < 2; j++) {
        accg[i][j] = __builtin_amdgcn_mfma_f32_16x16x32_bf16(af[i], bgf[j], accg[i][j], 0, 0, 0);
        accu[i][j] = __builtin_amdgcn_mfma_f32_16x16x32_bf16(af[i], buf2[j], accu[i][j], 0, 0, 0);
      }
    __syncthreads();
  }

#pragma unroll
  for (int i = 0; i < 4; i++) {
#pragma unroll
    for (int reg = 0; reg < 4; reg++) {
      int r = wm * 64 + i * 16 + quad * 4 + reg;
      if (r < nrows) {
        float w = roww[r];
#pragma unroll
        for (int j = 0; j < 2; j++) {
          float g = accg[i][j][reg], u = accu[i][j][reg];
          float h = g * u * w / (1.f + __expf(-g));
          H[(size_t)(row0 + r) * FDIM + f0 + wn * 32 + j * 16 + lrow] = f2b(h);
        }
      }
    }
  }
}

__global__ __launch_bounds__(256) void gemm2_f32_k(
    const unsigned short* __restrict__ H,
    const float* __restrict__ wd,
    const int* __restrict__ perm,
    const int4* __restrict__ tiles, const int* __restrict__ ntiles,
    float* __restrict__ out)
{
  __shared__ short Hs[128 * 32];
  __shared__ short Bs[64 * 32];
  __shared__ int rowtok[128];

  if (blockIdx.x >= *ntiles) return;
  int4 tm = tiles[blockIdx.x];
  int e = tm.x, row0 = tm.y, nrows = tm.z;
  int tid = threadIdx.x;
  if (tid < 128) {
    int r = tid < nrows ? tid : (nrows - 1);
    rowtok[tid] = perm[row0 + r] >> 1;
  }
  __syncthreads();

  int d0 = blockIdx.y * 64;
  int crow = tid >> 2, ccol = (tid & 3) * 8;
  const unsigned short* a0 = H + (size_t)(row0 + crow) * FDIM + ccol;
  const unsigned short* a1 = H + (size_t)(row0 + crow + 64) * FDIM + ccol;
  const float* b32 = wd + ((size_t)e * DIM + d0 + crow) * FDIM + ccol;
  short* hs0 = Hs + tid * 8;
  short* hs1 = Hs + (256 + tid) * 8;

  int wave = tid >> 6, lane = tid & 63;
  int wm = wave >> 1, wn = wave & 1;
  int lrow = lane & 15, quad = lane >> 4;

  f32x4 acc[4][2];
#pragma unroll
  for (int i = 0; i < 4; i++)
#pragma unroll
    for (int j = 0; j < 2; j++) acc[i][j] = (f32x4){0.f, 0.f, 0.f, 0.f};

  const short* arp = Hs + (wm * 64 + lrow) * 32 + quad * 8;
  const short* brp = Bs + (wn * 32 + lrow) * 32 + quad * 8;

#pragma unroll 1
  for (int k0 = 0; k0 < FDIM; k0 += 32) {
    async16(hs0, a0 + k0);
    async16(hs1, a1 + k0);
    float4 b0 = *(const float4*)(b32 + k0);
    float4 b1 = *(const float4*)(b32 + k0 + 4);
    short8 bsv;
    bsv[0] = f2b(b0.x); bsv[1] = f2b(b0.y); bsv[2] = f2b(b0.z); bsv[3] = f2b(b0.w);
    bsv[4] = f2b(b1.x); bsv[5] = f2b(b1.y); bsv[6] = f2b(b1.z); bsv[7] = f2b(b1.w);
    *(short8*)(Bs + tid * 8) = bsv;
    __syncthreads();
    short8 af[4], bf[2];
#pragma unroll
    for (int i = 0; i < 4; i++) af[i] = *(const short8*)(arp + i * 16 * 32);
#pragma unroll
    for (int j = 0; j < 2; j++) bf[j] = *(const short8*)(brp + j * 16 * 32);
#pragma unroll
    for (int i = 0; i < 4; i++)
#pragma unroll
      for (int j = 0; j < 2; j++)
        acc[i][j] = __builtin_amdgcn_mfma_f32_16x16x32_bf16(af[i], bf[j], acc[i][j], 0, 0, 0);
    __syncthreads();
  }

#pragma unroll
  for (int i = 0; i < 4; i++) {
#pragma unroll
    for (int reg = 0; reg < 4; reg++) {
      int r = wm * 64 + i * 16 + quad * 4 + reg;
      if (r < nrows) {
        int t = rowtok[r];
#pragma unroll
        for (int j = 0; j < 2; j++) {
          atomicAdd(&out[(size_t)t * DIM + d0 + wn * 32 + j * 16 + lrow], acc[i][j][reg]);
        }
      }
    }
  }
}

extern "C" void kernel_launch(void* const* d_in, const int* in_sizes, int n_in,
                              void* d_out, int out_size, void* d_ws, size_t ws_size,
                              hipStream_t stream)
{
  const float* x  = (const float*)d_in[0];
  const float* gw = (const float*)d_in[1];
  const float* wg = (const float*)d_in[2];
  const float* wu = (const float*)d_in[3];
  const float* wd = (const float*)d_in[4];
  float* out = (float*)d_out;
  float* logits_out = out + (size_t)T_TOK * DIM;

  char* ws = (char*)d_ws;
  float* topkw    = (float*)(ws + 0);                // 16 KB
  int*   topke    = (int*)(ws + 16384);              // 16 KB
  int*   counts   = (int*)(ws + 32768);              // 32 B (memset region 96 B)
  int*   ntiles128= (int*)(ws + 32896);
  int4*  tiles128 = (int4*)(ws + 33024);             // 40 slots
  int*   perm     = (int*)(ws + 35072);              // 16 KB
  int*   slot_of  = (int*)(ws + 51456);              // 16 KB (ends 67840)
  unsigned short* xb  = (unsigned short*)(ws + 131072);          // 8 MiB bf16 x
  unsigned short* H   = (unsigned short*)(ws + (9u  << 20));     // 8.65 MiB
  unsigned short* wgb = (unsigned short*)(ws + (18u << 20));     // 32 MiB
  unsigned short* wub = (unsigned short*)(ws + (50u << 20));     // 32 MiB
  const size_t WS_NEED_ALIAS = (size_t)82u  << 20;
  const size_t WS_NEED_FULL  = (size_t)146u << 20;

  hipMemsetAsync(counts, 0, 96, stream);

  if (ws_size >= WS_NEED_FULL) {
    unsigned short* wdb = (unsigned short*)(ws + (82u  << 20));  // 32 MiB
    float*          O   = (float*)         (ws + (114u << 20));  // 32 MiB
    // router + all three weight converts in one dispatch (independent work)
    front_k<<<512 + 6144, 256, 0, stream>>>(x, gw, topkw, topke, counts, logits_out, xb,
                                            wg, wgb, wu, wub, wd, wdb);
    scan_scatter_k<<<1, 256, 0, stream>>>(counts, topke, tiles128, ntiles128, perm, slot_of);
    gemm1_bf_k<<<dim3(FDIM / 64, MAXT128), 256, 0, stream>>>(xb, wgb, wub, perm, topkw, tiles128, ntiles128, H);
    gemm2_bf_k<<<dim3(DIM / 128, MAXT128), 256, 0, stream>>>(H, wdb, tiles128, ntiles128, O);
    combine_k<<<T_TOK, 256, 0, stream>>>(O, slot_of, out);
  } else if (ws_size >= WS_NEED_ALIAS) {
    unsigned short* wdb = wgb;                // gate/up weights dead after gemm1
    float*          O   = (float*)(ws + (50u << 20));   // aliases wub
    router_k<<<T_TOK / 4, 256, 0, stream>>>(x, gw, topkw, topke, counts, logits_out, xb);
    scan_scatter_k<<<1, 256, 0, stream>>>(counts, topke, tiles128, ntiles128, perm, slot_of);
    cvt2_k<<<16384, 256, 0, stream>>>(wg, wgb, wu, wub);
    gemm1_bf_k<<<dim3(FDIM / 64, MAXT128), 256, 0, stream>>>(xb, wgb, wub, perm, topkw, tiles128, ntiles128, H);
    cvt_w_k<<<8192, 256, 0, stream>>>(wd, wdb);   // after gemm1
    gemm2_bf_k<<<dim3(DIM / 128, MAXT128), 256, 0, stream>>>(H, wdb, tiles128, ntiles128, O);
    combine_k<<<T_TOK, 256, 0, stream>>>(O, slot_of, out);
  } else {
    router_k<<<T_TOK / 4, 256, 0, stream>>>(x, gw, topkw, topke, counts, logits_out, xb);
    scan_scatter_k<<<1, 256, 0, stream>>>(counts, topke, tiles128, ntiles128, perm, slot_of);
    hipMemsetAsync(d_out, 0, (size_t)T_TOK * DIM * sizeof(float), stream);
    gemm1_f32_k<<<dim3(MAXT128, FDIM / 64), 256, 0, stream>>>(xb, wg, wu, perm, topkw, tiles128, ntiles128, H);
    gemm2_f32_k<<<dim3(MAXT128, DIM / 64), 256, 0, stream>>>(H, wd, perm, tiles128, ntiles128, out);
  }
}

// Round 10
// 362.085 us; speedup vs baseline: 1.0362x; 1.0362x over previous
//
#include <hip/hip_runtime.h>
#include <stdint.h>

#define T_TOK 2048
#define DIM   2048
#define FDIM  1024
#define NE    8
#define MAXT128 40

typedef __attribute__((ext_vector_type(8))) short short8;
typedef __attribute__((ext_vector_type(4))) float f32x4;

__device__ __forceinline__ unsigned short f2b(float f) {
  union { float f; unsigned int i; } x; x.f = f;
  unsigned int r = x.i + 0x7fffu + ((x.i >> 16) & 1u);
  return (unsigned short)(r >> 16);
}

__device__ __forceinline__ void async16(void* lds, const void* g) {
  __builtin_amdgcn_global_load_lds(
      (const __attribute__((address_space(1))) void*)g,
      (__attribute__((address_space(3))) void*)lds, 16, 0, 0);
}

// ---------------- router (one wave per token) ----------------
__global__ __launch_bounds__(256) void router_k(
    const float* __restrict__ x, const float* __restrict__ gw,
    float* __restrict__ topkw, int* __restrict__ topke, int* __restrict__ counts,
    float* __restrict__ logits_out, unsigned short* __restrict__ xb)
{
  int wave = threadIdx.x >> 6, lane = threadIdx.x & 63;
  int t = blockIdx.x * 4 + wave;
  const float* xr = x + (size_t)t * DIM;
  unsigned short* xbr = xb + (size_t)t * DIM;
  float acc[NE];
#pragma unroll
  for (int e = 0; e < NE; e++) acc[e] = 0.f;
  for (int d = lane * 4; d < DIM; d += 256) {
    float4 xv = *(const float4*)(xr + d);
    ushort4 xo;
    xo.x = f2b(xv.x); xo.y = f2b(xv.y); xo.z = f2b(xv.z); xo.w = f2b(xv.w);
    *(ushort4*)(xbr + d) = xo;
#pragma unroll
    for (int e = 0; e < NE; e++) {
      float4 gv = *(const float4*)(gw + e * DIM + d);
      acc[e] += xv.x * gv.x + xv.y * gv.y + xv.z * gv.z + xv.w * gv.w;
    }
  }
#pragma unroll
  for (int off = 32; off > 0; off >>= 1) {
#pragma unroll
    for (int e = 0; e < NE; e++) acc[e] += __shfl_down(acc[e], off);
  }
  if (lane == 0) {
    float m = acc[0];
#pragma unroll
    for (int e = 1; e < NE; e++) m = fmaxf(m, acc[e]);
    float p[NE];
#pragma unroll
    for (int e = 0; e < NE; e++) p[e] = __expf(acc[e] - m);
    int e0 = 0;
#pragma unroll
    for (int e = 1; e < NE; e++) if (acc[e] > acc[e0]) e0 = e;
    int e1 = -1;
#pragma unroll
    for (int e = 0; e < NE; e++) if (e != e0 && (e1 < 0 || acc[e] > acc[e1])) e1 = e;
    float s = p[e0] + p[e1];
    topkw[t * 2] = p[e0] / s;
    topkw[t * 2 + 1] = p[e1] / s;
    topke[t * 2] = e0; topke[t * 2 + 1] = e1;
    atomicAdd(&counts[e0], 1);
    atomicAdd(&counts[e1], 1);
#pragma unroll
    for (int e = 0; e < NE; e++) logits_out[t * NE + e] = acc[e];
  }
}

// ---------------- fused scan + scatter (1 block) ----------------
__global__ __launch_bounds__(256) void scan_scatter_k(
    const int* __restrict__ counts, const int* __restrict__ topke,
    int4* __restrict__ tiles128, int* __restrict__ ntiles128,
    int* __restrict__ perm, int* __restrict__ slot_of)
{
  __shared__ int cur[NE];
  int tid = threadIdx.x;
  if (tid == 0) {
    int o = 0, nt2 = 0;
    for (int e = 0; e < NE; e++) {
      cur[e] = o;
      int c = counts[e];
      for (int r = 0; r < c; r += 128) {
        int rows = c - r < 128 ? c - r : 128;
        tiles128[nt2++] = make_int4(e, o + r, rows, 0);
      }
      o += c;
    }
    *ntiles128 = nt2;
  }
  __syncthreads();
  for (int i = tid; i < T_TOK * 2; i += 256) {
    int e = topke[i];
    int s = atomicAdd(&cur[e], 1);
    perm[s] = i;
    slot_of[i] = s;
  }
}

// ========== GEMM1: fp32 weights inline-converted, dbuf A (async) + dbuf B
// (one-tile-ahead ds_write), BM=128 BN=64, XCD-pinned grid.
// Grid: x = f-panel (16), y = row tile [0,40) | cvt-appendage [40,168) which
// converts wd->wdb using gemm1's idle memory bandwidth.
__global__ __launch_bounds__(256) void gemm1_k(
    const unsigned short* __restrict__ xb,
    const float* __restrict__ wg,
    const float* __restrict__ wu,
    const float* __restrict__ wd, unsigned short* __restrict__ wdb,
    const int* __restrict__ perm, const float* __restrict__ topkw,
    const int4* __restrict__ tiles, const int* __restrict__ ntiles,
    unsigned short* __restrict__ H)
{
  __shared__ short As[2][128 * 32];
  __shared__ short Bgs[2][64 * 32];
  __shared__ short Bus[2][64 * 32];
  __shared__ int rowtok[128];
  __shared__ float roww[128];

  int tid = threadIdx.x;

  if (blockIdx.y >= MAXT128) {
    // --- wd -> wdb conversion appendage (fills gemm1's idle bandwidth) ---
    int chunk = (blockIdx.y - MAXT128) * 16 + blockIdx.x;   // [0, 2048)
    size_t base = (size_t)chunk * 8192 + (size_t)tid * 8;
#pragma unroll
    for (int u = 0; u < 4; u++) {
      size_t i = base + (size_t)u * 2048;
      float4 a = *(const float4*)(wd + i);
      float4 b = *(const float4*)(wd + i + 4);
      ushort4 o0, o1;
      o0.x = f2b(a.x); o0.y = f2b(a.y); o0.z = f2b(a.z); o0.w = f2b(a.w);
      o1.x = f2b(b.x); o1.y = f2b(b.y); o1.z = f2b(b.z); o1.w = f2b(b.w);
      *(ushort4*)(wdb + i) = o0;
      *(ushort4*)(wdb + i + 4) = o1;
    }
    return;
  }

  if (blockIdx.y >= *ntiles) return;
  int4 tm = tiles[blockIdx.y];
  int e = tm.x, row0 = tm.y, nrows = tm.z;
  if (tid < 128) {
    int r = tid < nrows ? tid : (nrows - 1);
    int pid = perm[row0 + r];
    rowtok[tid] = pid >> 1;
    roww[tid] = topkw[pid];
  }
  __syncthreads();

  int f0 = blockIdx.x * 64;
  int crow = tid >> 2;            // 0..63
  int ccol = (tid & 3) * 8;
  const unsigned short* a0 = xb + (size_t)rowtok[crow] * DIM + ccol;
  const unsigned short* a1 = xb + (size_t)rowtok[crow + 64] * DIM + ccol;
  const float* bg32 = wg + ((size_t)e * FDIM + f0 + crow) * DIM + ccol;
  const float* bu32 = wu + ((size_t)e * FDIM + f0 + crow) * DIM + ccol;

  int wave = tid >> 6, lane = tid & 63;
  int wm = wave >> 1, wn = wave & 1;
  int lrow = lane & 15, quad = lane >> 4;

  f32x4 accg[4][2], accu[4][2];
#pragma unroll
  for (int i = 0; i < 4; i++)
#pragma unroll
    for (int j = 0; j < 2; j++) {
      accg[i][j] = (f32x4){0.f, 0.f, 0.f, 0.f};
      accu[i][j] = (f32x4){0.f, 0.f, 0.f, 0.f};
    }

  const int aoff = (wm * 64 + lrow) * 32 + quad * 8;
  const int boff = (wn * 32 + lrow) * 32 + quad * 8;

#define PACK_WRITE(bb, G0, G1, U0, U1)               \
  do {                                               \
    short8 gs, us;                                   \
    gs[0]=f2b(G0.x); gs[1]=f2b(G0.y); gs[2]=f2b(G0.z); gs[3]=f2b(G0.w); \
    gs[4]=f2b(G1.x); gs[5]=f2b(G1.y); gs[6]=f2b(G1.z); gs[7]=f2b(G1.w); \
    us[0]=f2b(U0.x); us[1]=f2b(U0.y); us[2]=f2b(U0.z); us[3]=f2b(U0.w); \
    us[4]=f2b(U1.x); us[5]=f2b(U1.y); us[6]=f2b(U1.z); us[7]=f2b(U1.w); \
    *(short8*)(&Bgs[bb][tid * 8]) = gs;              \
    *(short8*)(&Bus[bb][tid * 8]) = us;              \
  } while (0)

  // prologue: tile 0 -> Bbuf[0] + A async into As[0]; preload tile-1 regs
  {
    float4 g0 = *(const float4*)(bg32);
    float4 g1 = *(const float4*)(bg32 + 4);
    float4 u0 = *(const float4*)(bu32);
    float4 u1 = *(const float4*)(bu32 + 4);
    PACK_WRITE(0, g0, g1, u0, u1);
  }
  async16(&As[0][tid * 8], a0);
  async16(&As[0][(256 + tid) * 8], a1);
  float4 ng0 = *(const float4*)(bg32 + 32);
  float4 ng1 = *(const float4*)(bg32 + 36);
  float4 nu0 = *(const float4*)(bu32 + 32);
  float4 nu1 = *(const float4*)(bu32 + 36);

#pragma unroll 1
  for (int k0 = 0; k0 < DIM; k0 += 32) {
    int b = (k0 >> 5) & 1;
    __syncthreads();                 // As[b] drained; Bbuf[b] writes visible
    if (k0 + 32 < DIM) {
      async16(&As[b ^ 1][tid * 8], a0 + k0 + 32);
      async16(&As[b ^ 1][(256 + tid) * 8], a1 + k0 + 32);
      PACK_WRITE(b ^ 1, ng0, ng1, nu0, nu1);          // tile i+1 into Bbuf[b^1]
    }
    if (k0 + 64 < DIM) {                               // tile i+2 regs
      ng0 = *(const float4*)(bg32 + k0 + 64);
      ng1 = *(const float4*)(bg32 + k0 + 68);
      nu0 = *(const float4*)(bu32 + k0 + 64);
      nu1 = *(const float4*)(bu32 + k0 + 68);
    }
    const short* arp = &As[b][0] + aoff;
    const short* bgp = &Bgs[b][0] + boff;
    const short* bup = &Bus[b][0] + boff;
    short8 af[4], bgf[2], buf2[2];
#pragma unroll
    for (int i = 0; i < 4; i++) af[i] = *(const short8*)(arp + i * 16 * 32);
#pragma unroll
    for (int j = 0; j < 2; j++) {
      bgf[j]  = *(const short8*)(bgp + j * 16 * 32);
      buf2[j] = *(const short8*)(bup + j * 16 * 32);
    }
#pragma unroll
    for (int i = 0; i < 4; i++)
#pragma unroll
      for (int j = 0; j < 2; j++) {
        accg[i][j] = __builtin_amdgcn_mfma_f32_16x16x32_bf16(af[i], bgf[j], accg[i][j], 0, 0, 0);
        accu[i][j] = __builtin_amdgcn_mfma_f32_16x16x32_bf16(af[i], buf2[j], accu[i][j], 0, 0, 0);
      }
  }
#undef PACK_WRITE

#pragma unroll
  for (int i = 0; i < 4; i++) {
#pragma unroll
    for (int reg = 0; reg < 4; reg++) {
      int r = wm * 64 + i * 16 + quad * 4 + reg;
      if (r < nrows) {
        float w = roww[r];
#pragma unroll
        for (int j = 0; j < 2; j++) {
          float g = accg[i][j][reg], u = accu[i][j][reg];
          float h = g * u * w / (1.f + __expf(-g));
          H[(size_t)(row0 + r) * FDIM + f0 + wn * 32 + j * 16 + lrow] = f2b(h);
        }
      }
    }
  }
}

// GEMM2: O[slot,d] = H[slot,:] @ Wd[e]^T   BM=128, BN=128, bf16, no atomics
__global__ __launch_bounds__(256) void gemm2_bf_k(
    const unsigned short* __restrict__ H,
    const unsigned short* __restrict__ wdb,
    const int4* __restrict__ tiles, const int* __restrict__ ntiles,
    float* __restrict__ O)
{
  __shared__ short Hs[2][128 * 32];
  __shared__ short Bs[2][128 * 32];

  if (blockIdx.y >= *ntiles) return;
  int4 tm = tiles[blockIdx.y];
  int e = tm.x, row0 = tm.y, nrows = tm.z;
  int tid = threadIdx.x;

  int d0 = blockIdx.x * 128;
  int crow = tid >> 2, ccol = (tid & 3) * 8;
  const unsigned short* a0 = H + (size_t)(row0 + crow) * FDIM + ccol;
  const unsigned short* a1 = H + (size_t)(row0 + crow + 64) * FDIM + ccol;
  const unsigned short* b0 = wdb + ((size_t)e * DIM + d0 + crow) * FDIM + ccol;
  const unsigned short* b1 = b0 + (size_t)64 * FDIM;

  int wave = tid >> 6, lane = tid & 63;
  int wm = wave >> 1, wn = wave & 1;
  int lrow = lane & 15, quad = lane >> 4;

  f32x4 acc[4][4];
#pragma unroll
  for (int i = 0; i < 4; i++)
#pragma unroll
    for (int j = 0; j < 4; j++) acc[i][j] = (f32x4){0.f, 0.f, 0.f, 0.f};

  const int aoff = (wm * 64 + lrow) * 32 + quad * 8;
  const int boff = (wn * 64 + lrow) * 32 + quad * 8;

#define STAGE2(b, k)                                 \
  do {                                               \
    async16(&Hs[b][tid * 8], a0 + (k));              \
    async16(&Hs[b][(256 + tid) * 8], a1 + (k));      \
    async16(&Bs[b][tid * 8], b0 + (k));              \
    async16(&Bs[b][(256 + tid) * 8], b1 + (k));      \
  } while (0)

  STAGE2(0, 0);

#pragma unroll 1
  for (int k0 = 0; k0 < FDIM; k0 += 32) {
    int b = (k0 >> 5) & 1;
    __syncthreads();
    if (k0 + 32 < FDIM) STAGE2(b ^ 1, k0 + 32);
    const short* arp = &Hs[0][0] + b * (128 * 32) + aoff;
    const short* brp = &Bs[0][0] + b * (128 * 32) + boff;
    short8 af[4], bf[4];
#pragma unroll
    for (int i = 0; i < 4; i++) af[i] = *(const short8*)(arp + i * 16 * 32);
#pragma unroll
    for (int j = 0; j < 4; j++) bf[j] = *(const short8*)(brp + j * 16 * 32);
#pragma unroll
    for (int i = 0; i < 4; i++)
#pragma unroll
      for (int j = 0; j < 4; j++)
        acc[i][j] = __builtin_amdgcn_mfma_f32_16x16x32_bf16(af[i], bf[j], acc[i][j], 0, 0, 0);
  }
#undef STAGE2

#pragma unroll
  for (int i = 0; i < 4; i++) {
#pragma unroll
    for (int reg = 0; reg < 4; reg++) {
      int r = wm * 64 + i * 16 + quad * 4 + reg;
      if (r < nrows) {
#pragma unroll
        for (int j = 0; j < 4; j++) {
          O[(size_t)(row0 + r) * DIM + d0 + wn * 64 + j * 16 + lrow] = acc[i][j][reg];
        }
      }
    }
  }
}

// combine: out[t,:] = O[slot0(t),:] + O[slot1(t),:]
__global__ __launch_bounds__(256) void combine_k(
    const float* __restrict__ O, const int* __restrict__ slot_of,
    float* __restrict__ out)
{
  int t = blockIdx.x;
  int d = threadIdx.x * 8;
  int s0 = slot_of[2 * t], s1 = slot_of[2 * t + 1];
  const float4* p0 = (const float4*)(O + (size_t)s0 * DIM + d);
  const float4* p1 = (const float4*)(O + (size_t)s1 * DIM + d);
  float4 a0 = p0[0], a1 = p0[1], c0 = p1[0], c1 = p1[1];
  float4 r0, r1;
  r0.x = a0.x + c0.x; r0.y = a0.y + c0.y; r0.z = a0.z + c0.z; r0.w = a0.w + c0.w;
  r1.x = a1.x + c1.x; r1.y = a1.y + c1.y; r1.z = a1.z + c1.z; r1.w = a1.w + c1.w;
  float4* po = (float4*)(out + (size_t)t * DIM + d);
  po[0] = r0; po[1] = r1;
}

// ================= fp32 fallback path (proven r2 kernels) =================

__global__ __launch_bounds__(256) void gemm1_f32_k(
    const unsigned short* __restrict__ xb,
    const float* __restrict__ wg,
    const float* __restrict__ wu,
    const int* __restrict__ perm, const float* __restrict__ topkw,
    const int4* __restrict__ tiles, const int* __restrict__ ntiles,
    unsigned short* __restrict__ H)
{
  __shared__ short As[128 * 32];
  __shared__ short Bgs[64 * 32];
  __shared__ short Bus[64 * 32];
  __shared__ int rowtok[128];
  __shared__ float roww[128];

  if (blockIdx.x >= *ntiles) return;
  int4 tm = tiles[blockIdx.x];
  int e = tm.x, row0 = tm.y, nrows = tm.z;
  int tid = threadIdx.x;
  if (tid < 128) {
    int r = tid < nrows ? tid : (nrows - 1);
    int pid = perm[row0 + r];
    rowtok[tid] = pid >> 1;
    roww[tid] = topkw[pid];
  }
  __syncthreads();

  int f0 = blockIdx.y * 64;
  int crow = tid >> 2;
  int ccol = (tid & 3) * 8;
  const unsigned short* a0 = xb + (size_t)rowtok[crow] * DIM + ccol;
  const unsigned short* a1 = xb + (size_t)rowtok[crow + 64] * DIM + ccol;
  const float* bg32 = wg + ((size_t)e * FDIM + f0 + crow) * DIM + ccol;
  const float* bu32 = wu + ((size_t)e * FDIM + f0 + crow) * DIM + ccol;
  short* as0 = As + tid * 8;
  short* as1 = As + (256 + tid) * 8;

  int wave = tid >> 6, lane = tid & 63;
  int wm = wave >> 1, wn = wave & 1;
  int lrow = lane & 15, quad = lane >> 4;

  f32x4 accg[4][2], accu[4][2];
#pragma unroll
  for (int i = 0; i < 4; i++)
#pragma unroll
    for (int j = 0; j < 2; j++) {
      accg[i][j] = (f32x4){0.f, 0.f, 0.f, 0.f};
      accu[i][j] = (f32x4){0.f, 0.f, 0.f, 0.f};
    }

  const short* arp = As + (wm * 64 + lrow) * 32 + quad * 8;
  const short* bgp = Bgs + (wn * 32 + lrow) * 32 + quad * 8;
  const short* bup = Bus + (wn * 32 + lrow) * 32 + quad * 8;

#pragma unroll 1
  for (int k0 = 0; k0 < DIM; k0 += 32) {
    async16(as0, a0 + k0);
    async16(as1, a1 + k0);
    float4 g0 = *(const float4*)(bg32 + k0);
    float4 g1 = *(const float4*)(bg32 + k0 + 4);
    float4 u0 = *(const float4*)(bu32 + k0);
    float4 u1 = *(const float4*)(bu32 + k0 + 4);
    short8 gs, us;
    gs[0] = f2b(g0.x); gs[1] = f2b(g0.y); gs[2] = f2b(g0.z); gs[3] = f2b(g0.w);
    gs[4] = f2b(g1.x); gs[5] = f2b(g1.y); gs[6] = f2b(g1.z); gs[7] = f2b(g1.w);
    us[0] = f2b(u0.x); us[1] = f2b(u0.y); us[2] = f2b(u0.z); us[3] = f2b(u0.w);
    us[4] = f2b(u1.x); us[5] = f2b(u1.y); us[6] = f2b(u1.z); us[7] = f2b(u1.w);
    *(short8*)(Bgs + tid * 8) = gs;
    *(short8*)(Bus + tid * 8) = us;
    __syncthreads();
    short8 af[4], bgf[2], buf2[2];
#pragma unroll
    for (int i = 0; i < 4; i++) af[i] = *(const short8*)(arp + i * 16 * 32);
#pragma unroll
    for (int j = 0; j < 2; j++) {
      bgf[j]  = *(const short8*)(bgp + j * 16 * 32);
      buf2[j] = *(const short8*)(bup + j * 16 * 32);
    }
#pragma unroll
    for (int i = 0; i < 4; i++)
#pragma unroll
      for (int j = 0; j < 2; j++) {
        accg[i][j] = __builtin_amdgcn_mfma_f32_16x16x32_bf16(af[i], bgf[j], accg[i][j], 0, 0, 0);
        accu[i][j] = __builtin_amdgcn_mfma_f32_16x16x32_bf16(af[i], buf2[j], accu[i][j], 0, 0, 0);
      }
    __syncthreads();
  }

#pragma unroll
  for (int i = 0; i < 4; i++) {
#pragma unroll
    for (int reg = 0; reg < 4; reg++) {
      int r = wm * 64 + i * 16 + quad * 4 + reg;
      if (r < nrows) {
        float w = roww[r];
#pragma unroll
        for (int j = 0; j < 2; j++) {
          float g = accg[i][j][reg], u = accu[i][j][reg];
          float h = g * u * w / (1.f + __expf(-g));
          H[(size_t)(row0 + r) * FDIM + f0 + wn * 32 + j * 16 + lrow] = f2b(h);
        }
      }
    }
  }
}

__global__ __launch_bounds__(256) void gemm2_f32_k(
    const unsigned short* __restrict__ H,
    const float* __restrict__ wd,
    const int* __restrict__ perm,
    const int4* __restrict__ tiles, const int* __restrict__ ntiles,
    float* __restrict__ out)
{
  __shared__ short Hs[128 * 32];
  __shared__ short Bs[64 * 32];
  __shared__ int rowtok[128];

  if (blockIdx.x >= *ntiles) return;
  int4 tm = tiles[blockIdx.x];
  int e = tm.x, row0 = tm.y, nrows = tm.z;
  int tid = threadIdx.x;
  if (tid < 128) {
    int r = tid < nrows ? tid : (nrows - 1);
    rowtok[tid] = perm[row0 + r] >> 1;
  }
  __syncthreads();

  int d0 = blockIdx.y * 64;
  int crow = tid >> 2, ccol = (tid & 3) * 8;
  const unsigned short* a0 = H + (size_t)(row0 + crow) * FDIM + ccol;
  const unsigned short* a1 = H + (size_t)(row0 + crow + 64) * FDIM + ccol;
  const float* b32 = wd + ((size_t)e * DIM + d0 + crow) * FDIM + ccol;
  short* hs0 = Hs + tid * 8;
  short* hs1 = Hs + (256 + tid) * 8;

  int wave = tid >> 6, lane = tid & 63;
  int wm = wave >> 1, wn = wave & 1;
  int lrow = lane & 15, quad = lane >> 4;

  f32x4 acc[4][2];
#pragma unroll
  for (int i = 0; i < 4; i++)
#pragma unroll
    for (int j = 0; j < 2; j++) acc[i][j] = (f32x4){0.f, 0.f, 0.f, 0.f};

  const short* arp = Hs + (wm * 64 + lrow) * 32 + quad * 8;
  const short* brp = Bs + (wn * 32 + lrow) * 32 + quad * 8;

#pragma unroll 1
  for (int k0 = 0; k0 < FDIM; k0 += 32) {
    async16(hs0, a0 + k0);
    async16(hs1, a1 + k0);
    float4 b0 = *(const float4*)(b32 + k0);
    float4 b1 = *(const float4*)(b32 + k0 + 4);
    short8 bsv;
    bsv[0] = f2b(b0.x); bsv[1] = f2b(b0.y); bsv[2] = f2b(b0.z); bsv[3] = f2b(b0.w);
    bsv[4] = f2b(b1.x); bsv[5] = f2b(b1.y); bsv[6] = f2b(b1.z); bsv[7] = f2b(b1.w);
    *(short8*)(Bs + tid * 8) = bsv;
    __syncthreads();
    short8 af[4], bf[2];
#pragma unroll
    for (int i = 0; i < 4; i++) af[i] = *(const short8*)(arp + i * 16 * 32);
#pragma unroll
    for (int j = 0; j < 2; j++) bf[j] = *(const short8*)(brp + j * 16 * 32);
#pragma unroll
    for (int i = 0; i < 4; i++)
#pragma unroll
      for (int j = 0; j < 2; j++)
        acc[i][j] = __builtin_amdgcn_mfma_f32_16x16x32_bf16(af[i], bf[j], acc[i][j], 0, 0, 0);
    __syncthreads();
  }

#pragma unroll
  for (int i = 0; i < 4; i++) {
#pragma unroll
    for (int reg = 0; reg < 4; reg++) {
      int r = wm * 64 + i * 16 + quad * 4 + reg;
      if (r < nrows) {
        int t = rowtok[r];
#pragma unroll
        for (int j = 0; j < 2; j++) {
          atomicAdd(&out[(size_t)t * DIM + d0 + wn * 32 + j * 16 + lrow], acc[i][j][reg]);
        }
      }
    }
  }
}

extern "C" void kernel_launch(void* const* d_in, const int* in_sizes, int n_in,
                              void* d_out, int out_size, void* d_ws, size_t ws_size,
                              hipStream_t stream)
{
  const float* x  = (const float*)d_in[0];
  const float* gw = (const float*)d_in[1];
  const float* wg = (const float*)d_in[2];
  const float* wu = (const float*)d_in[3];
  const float* wd = (const float*)d_in[4];
  float* out = (float*)d_out;
  float* logits_out = out + (size_t)T_TOK * DIM;

  char* ws = (char*)d_ws;
  float* topkw    = (float*)(ws + 0);                // 16 KB
  int*   topke    = (int*)(ws + 16384);              // 16 KB
  int*   counts   = (int*)(ws + 32768);              // 32 B (memset region 96 B)
  int*   ntiles128= (int*)(ws + 32896);
  int4*  tiles128 = (int4*)(ws + 33024);             // 40 slots
  int*   perm     = (int*)(ws + 35072);              // 16 KB
  int*   slot_of  = (int*)(ws + 51456);              // 16 KB (ends 67840)
  unsigned short* xb  = (unsigned short*)(ws + 131072);          // 8 MiB bf16 x
  unsigned short* H   = (unsigned short*)(ws + (9u  << 20));     // 8.65 MiB
  unsigned short* wdb = (unsigned short*)(ws + (18u << 20));     // 32 MiB
  float*          O   = (float*)         (ws + (50u << 20));     // 32 MiB (ends 82 MiB)
  const size_t WS_NEED = (size_t)82u << 20;

  hipMemsetAsync(counts, 0, 96, stream);

  router_k<<<T_TOK / 4, 256, 0, stream>>>(x, gw, topkw, topke, counts, logits_out, xb);
  scan_scatter_k<<<1, 256, 0, stream>>>(counts, topke, tiles128, ntiles128, perm, slot_of);

  if (ws_size >= WS_NEED) {
    // gemm1 (fp32 weights inline) + wd->bf16 conversion appended to its grid
    gemm1_k<<<dim3(FDIM / 64, MAXT128 + 128), 256, 0, stream>>>(
        xb, wg, wu, wd, wdb, perm, topkw, tiles128, ntiles128, H);
    gemm2_bf_k<<<dim3(DIM / 128, MAXT128), 256, 0, stream>>>(H, wdb, tiles128, ntiles128, O);
    combine_k<<<T_TOK, 256, 0, stream>>>(O, slot_of, out);
  } else {
    hipMemsetAsync(d_out, 0, (size_t)T_TOK * DIM * sizeof(float), stream);
    gemm1_f32_k<<<dim3(MAXT128, FDIM / 64), 256, 0, stream>>>(xb, wg, wu, perm, topkw, tiles128, ntiles128, H);
    gemm2_f32_k<<<dim3(MAXT128, DIM / 64), 256, 0, stream>>>(H, wd, perm, tiles128, ntiles128, out);
  }
}